// Round 2
// baseline (298.292 us; speedup 1.0000x reference)
//
#include <hip/hip_runtime.h>

typedef short  short8  __attribute__((ext_vector_type(8)));
typedef short  short4v __attribute__((ext_vector_type(4)));
typedef float  float4v __attribute__((ext_vector_type(4)));
typedef int    int4v   __attribute__((ext_vector_type(4)));

#define LOG2E 1.4426950408889634f

static __device__ __forceinline__ short f2bf(float f) {
  unsigned u = __builtin_bit_cast(unsigned, f);
  u = (u + 0x7fffu + ((u >> 16) & 1u)) >> 16;   // RNE
  return (short)u;
}
static __device__ __forceinline__ float bf2f(short s) {
  return __builtin_bit_cast(float, ((unsigned)(unsigned short)s) << 16);
}

// ---------------------------------------------------------------------------
// Kernel 1: h = x @ w.T  (8192x256, K=256), hi/lo bf16-split MFMA for ~f32
// accuracy. Writes hT bf16 [256][8192] (ws) and hT f32 [256][8192] (d_out,
// transient scratch — k_gat overwrites d_out later).
// ---------------------------------------------------------------------------
__global__ __launch_bounds__(256) void k_hgemm(
    const float* __restrict__ x, const float* __restrict__ w,
    short* __restrict__ hT, float* __restrict__ hTf) {
  const int I0   = blockIdx.x * 64;
  const int lane = threadIdx.x & 63;
  const int wn   = threadIdx.x >> 6;       // 4 waves split N (cols)
  const int lrow = lane & 15;
  const int lk8  = (lane >> 4) << 3;

  float4v zero4 = {0.f, 0.f, 0.f, 0.f};
  float4v acc[4][4];
  #pragma unroll
  for (int mi = 0; mi < 4; ++mi)
    #pragma unroll
    for (int ni = 0; ni < 4; ++ni) acc[mi][ni] = zero4;

  for (int k0 = 0; k0 < 256; k0 += 32) {
    short8 ah[4], al[4], bh[4], bl[4];
    #pragma unroll
    for (int mi = 0; mi < 4; ++mi) {
      const float* xp = x + (size_t)(I0 + mi * 16 + lrow) * 256 + k0 + lk8;
      float4v va = *(const float4v*)xp;
      float4v vb = *(const float4v*)(xp + 4);
      #pragma unroll
      for (int e = 0; e < 4; ++e) {
        short h = f2bf(va[e]); ah[mi][e] = h;     al[mi][e]     = f2bf(va[e] - bf2f(h));
        h = f2bf(vb[e]);       ah[mi][4 + e] = h; al[mi][4 + e] = f2bf(vb[e] - bf2f(h));
      }
    }
    #pragma unroll
    for (int ni = 0; ni < 4; ++ni) {
      const float* wp = w + (size_t)(wn * 64 + ni * 16 + lrow) * 256 + k0 + lk8;
      float4v va = *(const float4v*)wp;
      float4v vb = *(const float4v*)(wp + 4);
      #pragma unroll
      for (int e = 0; e < 4; ++e) {
        short h = f2bf(va[e]); bh[ni][e] = h;     bl[ni][e]     = f2bf(va[e] - bf2f(h));
        h = f2bf(vb[e]);       bh[ni][4 + e] = h; bl[ni][4 + e] = f2bf(vb[e] - bf2f(h));
      }
    }
    #pragma unroll
    for (int mi = 0; mi < 4; ++mi)
      #pragma unroll
      for (int ni = 0; ni < 4; ++ni) {
        acc[mi][ni] = __builtin_amdgcn_mfma_f32_16x16x32_bf16(al[mi], bh[ni], acc[mi][ni], 0, 0, 0);
        acc[mi][ni] = __builtin_amdgcn_mfma_f32_16x16x32_bf16(ah[mi], bl[ni], acc[mi][ni], 0, 0, 0);
        acc[mi][ni] = __builtin_amdgcn_mfma_f32_16x16x32_bf16(ah[mi], bh[ni], acc[mi][ni], 0, 0, 0);
      }
  }
  const int r0 = (lane >> 4) << 2;   // C/D: col=lane&15, row=(lane>>4)*4+reg
  #pragma unroll
  for (int mi = 0; mi < 4; ++mi)
    #pragma unroll
    for (int ni = 0; ni < 4; ++ni) {
      const int c   = wn * 64 + ni * 16 + lrow;
      const int row = I0 + mi * 16 + r0;
      float4v v = acc[mi][ni];
      short4v sv;
      #pragma unroll
      for (int r = 0; r < 4; ++r) sv[r] = f2bf(v[r]);
      *(short4v*)(hT + (size_t)c * 8192 + row) = sv;
      *(float4v*)(hTf + (size_t)c * 8192 + row) = v;
    }
}

// ---------------------------------------------------------------------------
// Kernel 2/3: s1 = h@a1, s2 = h@a2, pre-scaled by log2(e)  (split-K + reduce)
// ---------------------------------------------------------------------------
__global__ __launch_bounds__(256) void k_scores1(
    const float* __restrict__ hTf, const float* __restrict__ a,
    float* __restrict__ t1p, float* __restrict__ t2p) {
  const int i = blockIdx.x * 256 + threadIdx.x;
  const int q = blockIdx.y;
  float s1 = 0.f, s2 = 0.f;
  #pragma unroll 8
  for (int kf = q * 64; kf < q * 64 + 64; ++kf) {
    float hv = hTf[(size_t)kf * 8192 + i];
    s1 = fmaf(hv, a[kf], s1);
    s2 = fmaf(hv, a[256 + kf], s2);
  }
  t1p[q * 8192 + i] = s1;
  t2p[q * 8192 + i] = s2;
}

__global__ __launch_bounds__(256) void k_scores2(
    const float* __restrict__ t1p, const float* __restrict__ t2p,
    float* __restrict__ t1, float* __restrict__ t2) {
  const int i = blockIdx.x * 256 + threadIdx.x;
  t1[i] = LOG2E * (t1p[i] + t1p[8192 + i] + t1p[16384 + i] + t1p[24576 + i]);
  t2[i] = LOG2E * (t2p[i] + t2p[8192 + i] + t2p[16384 + i] + t2p[24576 + i]);
}

// ---------------------------------------------------------------------------
// Kernel 4: fused GAT body, BM=32, split-K=1 (256 blocks x 512 threads).
// Per step (64 j's): W_ij = adj ? exp2(leakyscaled(t1_i + t2_j)) : 1 in regs,
// staged to XOR-swizzled double-buffered LDS, one __syncthreads per step,
// consumed by mfma_16x16x32_bf16 against per-lane hT B-frags (L2-hot, all
// blocks co-stream the same j-window). Z accumulated in f32; out = elu(N/Z)
// written directly (no split-K partials, no extra passes).
// ---------------------------------------------------------------------------
__global__ __launch_bounds__(512, 2) void k_gat(
    const int* __restrict__ adj, const short* __restrict__ hT,
    const float* __restrict__ t1, const float* __restrict__ t2,
    float* __restrict__ out) {
  __shared__ __align__(16) char Wlds[2][4096];   // 32 rows x 128B, swizzled
  __shared__ float zlds[512];
  __shared__ float zrow[32];

  const int I0 = blockIdx.x * 32;
  const int tid = threadIdx.x, lane = tid & 63, wave = tid >> 6;
  const int wm = wave >> 2, wn = wave & 3;       // 2 row-groups x 4 col-groups
  const int lrow = lane & 15, lk8 = (lane >> 4) << 3;

  // staging mapping: thread -> (row, 4-wide j-group)
  const int srow = tid >> 4, sjg = tid & 15;
  const float t1v = t1[I0 + srow];
  const int woff = srow * 128 + ((((sjg >> 1) << 4)) ^ ((srow & 7) << 4))
                 + ((sjg & 1) << 3);

  const int* ap = adj + (size_t)(I0 + srow) * 8192 + sjg * 4;
  const float* tp = t2 + sjg * 4;
  const char* bp[8];
  #pragma unroll
  for (int ni = 0; ni < 4; ++ni)
    #pragma unroll
    for (int kk = 0; kk < 2; ++kk)
      bp[ni * 2 + kk] = (const char*)hT
          + (size_t)(wn * 64 + ni * 16 + lrow) * 16384
          + (size_t)(kk * 32 + lk8) * 2;

  const int arow = wm * 16 + lrow;
  const int aoff0 = arow * 128 + (((lk8 << 1)) ^ ((arow & 7) << 4));
  const int aoff1 = arow * 128 + ((64 + (lk8 << 1)) ^ ((arow & 7) << 4));

  float4v zero4 = {0.f, 0.f, 0.f, 0.f};
  float4v acc[4] = {zero4, zero4, zero4, zero4};
  float zacc = 0.f;

  // prologue: step-0 data
  int4v ca = __builtin_nontemporal_load((const int4v*)ap);
  float4v ct = *(const float4v*)tp;
  short8 bcur[8];
  #pragma unroll
  for (int i = 0; i < 8; ++i) bcur[i] = *(const short8*)bp[i];

  #pragma unroll 2
  for (int s = 0; s < 128; ++s) {
    const int sn = (s + 1) & 127;   // wraps to 0 on last iter (discarded)
    // issue next-step loads early
    int4v na = __builtin_nontemporal_load((const int4v*)(ap + sn * 64));
    float4v nt = *(const float4v*)(tp + sn * 64);
    short8 bnxt[8];
    #pragma unroll
    for (int i = 0; i < 8; ++i) bnxt[i] = *(const short8*)(bp[i] + sn * 128);

    // compute W for step s (regs), accumulate Z in f32
    short4v pw;
    #pragma unroll
    for (int e = 0; e < 4; ++e) {
      float sc = t1v + ct[e];
      float ex = exp2f(fmaxf(sc, 0.2f * sc));
      float wv = (ca[e] != 0) ? ex : 1.0f;
      zacc += wv;
      pw[e] = f2bf(wv);
    }
    char* wbuf = Wlds[0] + (s & 1) * 4096;
    *(short4v*)(wbuf + woff) = pw;     // swizzled ds_write_b64
    __syncthreads();                   // one barrier/step (dbuf makes it safe)

    short8 af0 = *(const short8*)(wbuf + aoff0);
    short8 af1 = *(const short8*)(wbuf + aoff1);
    #pragma unroll
    for (int ni = 0; ni < 4; ++ni)
      acc[ni] = __builtin_amdgcn_mfma_f32_16x16x32_bf16(af0, bcur[ni * 2 + 0], acc[ni], 0, 0, 0);
    #pragma unroll
    for (int ni = 0; ni < 4; ++ni)
      acc[ni] = __builtin_amdgcn_mfma_f32_16x16x32_bf16(af1, bcur[ni * 2 + 1], acc[ni], 0, 0, 0);

    ca = na; ct = nt;
    #pragma unroll
    for (int i = 0; i < 8; ++i) bcur[i] = bnxt[i];
  }

  // Z: reduce 16 j-group partials per row, broadcast via LDS
  zlds[tid] = zacc;
  __syncthreads();
  if (tid < 32) {
    float z = 0.f;
    #pragma unroll
    for (int g = 0; g < 16; ++g) z += zlds[tid * 16 + g];
    zrow[tid] = z;
  }
  __syncthreads();

  // epilogue: out = elu(N/Z), written directly
  const int r0 = (lane >> 4) << 2;
  #pragma unroll
  for (int ni = 0; ni < 4; ++ni) {
    const int col = wn * 64 + ni * 16 + lrow;
    #pragma unroll
    for (int r = 0; r < 4; ++r) {
      const int row = wm * 16 + r0 + r;
      float v = acc[ni][r] / zrow[row];
      out[(size_t)(I0 + row) * 256 + col] = (v > 0.f) ? v : expm1f(v);
    }
  }
}

// ---------------------------------------------------------------------------
extern "C" void kernel_launch(void* const* d_in, const int* in_sizes, int n_in,
                              void* d_out, int out_size, void* d_ws, size_t ws_size,
                              hipStream_t stream) {
  const int*   adj = (const int*)d_in[0];
  const float* x   = (const float*)d_in[1];
  const float* w   = (const float*)d_in[2];
  const float* a   = (const float*)d_in[3];
  float* out = (float*)d_out;

  // ws usage: 4.32 MiB total (hT 4MiB + score buffers). hTf (8MB f32) lives
  // in d_out transiently; k_gat overwrites d_out with the final output.
  char* ws = (char*)d_ws;
  short* hT  = (short*)(ws + 0);          // 4 MiB   bf16 h^T [256][8192]
  float* t1p = (float*)(ws + 4194304);    // 128 KiB
  float* t2p = (float*)(ws + 4325376);    // 128 KiB
  float* t1  = (float*)(ws + 4456448);    // 32 KiB
  float* t2  = (float*)(ws + 4489216);    // 32 KiB
  float* hTf = (float*)d_out;             // 8 MiB   f32 h^T (transient)

  k_hgemm  <<<128, 256, 0, stream>>>(x, w, hT, hTf);
  k_scores1<<<dim3(32, 4), 256, 0, stream>>>(hTf, a, t1p, t2p);
  k_scores2<<<32, 256, 0, stream>>>(t1p, t2p, t1, t2);
  k_gat    <<<256, 512, 0, stream>>>(adj, hT, t1, t2, out);
}